// Round 1
// baseline (299.832 us; speedup 1.0000x reference)
//
#include <hip/hip_runtime.h>
#include <stdint.h>

// PRNG layout for jax.random bits:
//  0 = legacy/original (split-halves over the flat array)
//  1 = partitionable counter-mode, bits = y0 ^ y1   (modern JAX default; best guess)
//  2 = partitionable, bits = y0
//  3 = partitionable, bits = y1
#define PRNG_VARIANT 1

#define NB 8
#define NT 4096
#define ND 512
#define NH 512
#define NTOK (NB * NT)

typedef __attribute__((ext_vector_type(8))) short short8;
typedef __attribute__((ext_vector_type(4))) float f32x4;

// ---- workspace layout (bytes) ----
#define WS_WEX   0          // 512*2 f64   : W_embed @ Wx
#define WS_PEX   8192       // 4096*2 f64  : (b_embed + pe[t]) @ Wx
#define WS_VWV   73728      // 2*8*2 f64   : v_i @ Wv
#define WS_KEYS  73984      // 4 u32       : fold_in keys
#define WS_MASK  74016      // NTOK i32
#define WS_SEL   205088     // NTOK i32
#define WS_LENS  336160     // 8 i32
#define WS_WT    336192     // 512*512 u16 : bf16 W_embed transposed [n][k]

__device__ inline void threefry2x32(uint32_t k0, uint32_t k1, uint32_t x0, uint32_t x1,
                                    uint32_t& y0, uint32_t& y1) {
  uint32_t ks2 = k0 ^ k1 ^ 0x1BD11BDAu;
  x0 += k0; x1 += k1;
#define TFR(r) { x0 += x1; x1 = (x1 << (r)) | (x1 >> (32 - (r))); x1 ^= x0; }
  TFR(13) TFR(15) TFR(26) TFR(6)   x0 += k1;  x1 += ks2 + 1u;
  TFR(17) TFR(29) TFR(16) TFR(24)  x0 += ks2; x1 += k0 + 2u;
  TFR(13) TFR(15) TFR(26) TFR(6)   x0 += k0;  x1 += k1 + 3u;
  TFR(17) TFR(29) TFR(16) TFR(24)  x0 += k1;  x1 += ks2 + 4u;
  TFR(13) TFR(15) TFR(26) TFR(6)   x0 += ks2; x1 += k0 + 5u;
#undef TFR
  y0 = x0; y1 = x1;
}

// random bits for flat index idx in an array of 65536 uint32 draws
__device__ inline uint32_t rb_bits(uint32_t k0, uint32_t k1, uint32_t idx) {
#if PRNG_VARIANT == 0
  uint32_t y0, y1;
  if (idx < 32768u) { threefry2x32(k0, k1, idx, idx + 32768u, y0, y1); return y0; }
  else              { threefry2x32(k0, k1, idx - 32768u, idx, y0, y1); return y1; }
#else
  uint32_t y0, y1;
  threefry2x32(k0, k1, 0u, idx, y0, y1);
#if PRNG_VARIANT == 1
  return y0 ^ y1;
#elif PRNG_VARIANT == 2
  return y0;
#else
  return y1;
#endif
#endif
}

__device__ inline double gumbel_from_bits(uint32_t bits) {
  uint32_t m = bits >> 9;
  // jax uniform(minval=tiny32, maxval=1): u = m ? m*2^-23 : FLT_MIN
  float u = m ? (float)m * 1.1920928955078125e-07f : 1.17549435082228751e-38f;
  double lu = log((double)u);
  return -log(-lu);
}

__device__ inline uint16_t f2bf(float f) {
  union { float f; uint32_t u; } v; v.f = f;
  uint32_t u = v.u;
  return (uint16_t)((u + 0x7FFFu + ((u >> 16) & 1u)) >> 16);
}

__device__ inline double wredd(double v) {
#pragma unroll
  for (int o = 32; o > 0; o >>= 1) v += __shfl_xor(v, o, 64);
  return v;
}

// ---- k_prep: fp64 reduced operands + bf16 W^T + PRNG keys ----
__global__ __launch_bounds__(64) void k_prep(
    const float* __restrict__ v0, const float* __restrict__ v1,
    const float* __restrict__ W, const float* __restrict__ be,
    const float* __restrict__ Wx, const float* __restrict__ Wv,
    char* __restrict__ ws) {
  double* Wex = (double*)(ws + WS_WEX);
  double* pex = (double*)(ws + WS_PEX);
  double* vWv = (double*)(ws + WS_VWV);
  uint32_t* keys = (uint32_t*)(ws + WS_KEYS);
  uint16_t* Wt = (uint16_t*)(ws + WS_WT);
  int blk = blockIdx.x;
  int lane = threadIdx.x;

  if (blk < 512) {                       // Wex[d][j] = sum_h W[d][h] * Wx[h][j]
    int d = blk;
    double a0 = 0.0, a1 = 0.0;
    for (int it = 0; it < 8; ++it) {
      int h = it * 64 + lane;
      double w = (double)W[d * 512 + h];
      a0 += w * (double)Wx[2 * h];
      a1 += w * (double)Wx[2 * h + 1];
    }
    a0 = wredd(a0); a1 = wredd(a1);
    if (lane == 0) { Wex[2 * d] = a0; Wex[2 * d + 1] = a1; }
  } else if (blk < 4608) {               // pex[t][j] = sum_h (be[h]+pe[t][h]) * Wx[h][j]
    int t = blk - 512;
    double a0 = 0.0, a1 = 0.0;
    const double c = -9.210340371976184 / 512.0;  // -ln(10000)/H
    for (int it = 0; it < 8; ++it) {
      int h = it * 64 + lane;
      double div = exp((double)((h >> 1) * 2) * c);
      double ph = (double)t * div;
      double pe = (h & 1) ? cos(ph) : sin(ph);
      double pb = pe + (double)be[h];
      a0 += pb * (double)Wx[2 * h];
      a1 += pb * (double)Wx[2 * h + 1];
    }
    a0 = wredd(a0); a1 = wredd(a1);
    if (lane == 0) { pex[2 * t] = a0; pex[2 * t + 1] = a1; }
  } else if (blk < 4624) {               // vWv[i][b][j]
    int q = blk - 4608;
    int i = q >> 3, b = q & 7;
    const float* v = i ? v1 : v0;
    double a0 = 0.0, a1 = 0.0;
    for (int it = 0; it < 8; ++it) {
      int d = it * 64 + lane;
      double x = (double)v[b * 512 + d];
      a0 += x * (double)Wv[2 * d];
      a1 += x * (double)Wv[2 * d + 1];
    }
    a0 = wredd(a0); a1 = wredd(a1);
    if (lane == 0) { vWv[(i * 8 + b) * 2] = a0; vWv[(i * 8 + b) * 2 + 1] = a1; }
  } else if (blk < 5136) {               // Wt[n][k] = bf16(W[k][n])
    int kk = blk - 4624;
    for (int it = 0; it < 8; ++it) {
      int n = it * 64 + lane;
      Wt[(size_t)n * 512 + kk] = f2bf(W[kk * 512 + n]);
    }
  } else {                               // derived keys: fold_in(key(42), i)
    if (lane < 2) {
      uint32_t y0, y1;
      threefry2x32(0u, 42u, 0u, (uint32_t)lane, y0, y1);
      keys[lane * 2] = y0; keys[lane * 2 + 1] = y1;
    }
  }
}

// ---- k_decide: one wave per token; fp64 logits + exact threefry gumbel -> mask ----
__global__ __launch_bounds__(256) void k_decide(
    const float* __restrict__ data, const float* __restrict__ bfp,
    const char* __restrict__ wsc, int* __restrict__ mask) {
  const double* Wex = (const double*)(wsc + WS_WEX);
  const double* pex = (const double*)(wsc + WS_PEX);
  const double* vWv = (const double*)(wsc + WS_VWV);
  const uint32_t* keys = (const uint32_t*)(wsc + WS_KEYS);

  int k = blockIdx.x * 4 + (threadIdx.x >> 6);
  int lane = threadIdx.x & 63;
  int b = k >> 12;
  int t = k & 4095;

  const float4* dp = (const float4*)(data + (size_t)k * 512 + lane * 8);
  float4 f0 = dp[0], f1 = dp[1];
  float xv[8] = {f0.x, f0.y, f0.z, f0.w, f1.x, f1.y, f1.z, f1.w};
  const double* wx = Wex + lane * 16;
  double d0 = 0.0, d1 = 0.0;
#pragma unroll
  for (int u = 0; u < 8; ++u) {
    double x = (double)xv[u];
    d0 += x * wx[2 * u];
    d1 += x * wx[2 * u + 1];
  }
  d0 = wredd(d0); d1 = wredd(d1);

  int dec = 0;
  if (lane < 4) {
    int i = lane >> 1, j = lane & 1;
    double lj = 8.0 * ((j ? d1 : d0) + pex[t * 2 + j]) + vWv[(i * 8 + b) * 2 + j] + (double)bfp[j];
    uint32_t bits = rb_bits(keys[i * 2], keys[i * 2 + 1], (uint32_t)(2 * k + j));
    double z = lj + gumbel_from_bits(bits);
    double zo = __shfl_xor(z, 1, 64);
    dec = (z >= zo) ? 1 : 0;  // meaningful on lanes 0 (i=0) and 2 (i=1): class0 wins
  }
  int dA = __shfl(dec, 0, 64);
  int dB = __shfl(dec, 2, 64);
  if (lane == 0) mask[k] = dA & dB;
}

// ---- k_scan: stable per-row compaction indices ----
__global__ __launch_bounds__(1024) void k_scan(
    const int* __restrict__ mask, int* __restrict__ sel, int* __restrict__ lens) {
  __shared__ int cnt[1024];
  int b = blockIdx.x, tid = threadIdx.x;
  int t0 = tid * 4;
  int m[4], p = 0;
#pragma unroll
  for (int u = 0; u < 4; ++u) { m[u] = mask[b * 4096 + t0 + u]; p += m[u]; }
  cnt[tid] = p;
  __syncthreads();
  for (int off = 1; off < 1024; off <<= 1) {
    int v = (tid >= off) ? cnt[tid - off] : 0;
    __syncthreads();
    cnt[tid] += v;
    __syncthreads();
  }
  int run = cnt[tid] - p;  // exclusive prefix
#pragma unroll
  for (int u = 0; u < 4; ++u) {
    if (m[u]) { sel[b * 4096 + run] = t0 + u; ++run; }
  }
  if (tid == 1023) lens[b] = cnt[1023];
}

// ---- k_gemm: bf16 MFMA on gathered rows; full output coverage (zeros past lens) ----
__global__ __launch_bounds__(256) void k_gemm(
    const float* __restrict__ data, const float* __restrict__ be,
    const char* __restrict__ wsc, float* __restrict__ out) {
  const uint16_t* Wt = (const uint16_t*)(wsc + WS_WT);
  const int* sel = (const int*)(wsc + WS_SEL);
  const int* lens = (const int*)(wsc + WS_LENS);

  int mb = blockIdx.x, nb = blockIdx.y, b = blockIdx.z;
  int wave = threadIdx.x >> 6, lane = threadIdx.x & 63;
  int quad = lane >> 4, l15 = lane & 15;
  int lensb = lens[b];
  int jbase = mb * 64 + wave * 16;

  f32x4 acc[4] = {{0.f,0.f,0.f,0.f},{0.f,0.f,0.f,0.f},{0.f,0.f,0.f,0.f},{0.f,0.f,0.f,0.f}};

  if (jbase < lensb) {
    int jA = jbase + l15;
    bool validA = jA < lensb;
    int tA = validA ? sel[b * 4096 + jA] : 0;
    const float* ap = data + ((size_t)b * 4096 + tA) * 512 + quad * 8;
    const uint16_t* bp = Wt + ((size_t)(nb * 64 + l15)) * 512 + quad * 8;
    for (int k0 = 0; k0 < 512; k0 += 32) {
      short8 afrag;
      if (validA) {
        float4 a0 = *(const float4*)(ap + k0);
        float4 a1 = *(const float4*)(ap + k0 + 4);
        afrag[0] = (short)f2bf(a0.x); afrag[1] = (short)f2bf(a0.y);
        afrag[2] = (short)f2bf(a0.z); afrag[3] = (short)f2bf(a0.w);
        afrag[4] = (short)f2bf(a1.x); afrag[5] = (short)f2bf(a1.y);
        afrag[6] = (short)f2bf(a1.z); afrag[7] = (short)f2bf(a1.w);
      } else {
        afrag[0]=0; afrag[1]=0; afrag[2]=0; afrag[3]=0;
        afrag[4]=0; afrag[5]=0; afrag[6]=0; afrag[7]=0;
      }
#pragma unroll
      for (int f = 0; f < 4; ++f) {
        short8 bfrag = *(const short8*)(bp + (size_t)f * 16 * 512 + k0);
        acc[f] = __builtin_amdgcn_mfma_f32_16x16x32_bf16(afrag, bfrag, acc[f], 0, 0, 0);
      }
    }
  }

  int trow[4];
#pragma unroll
  for (int r = 0; r < 4; ++r) {
    int j = jbase + quad * 4 + r;
    trow[r] = (j < lensb) ? sel[b * 4096 + j] : -1;
  }
  const float c1 = -0.01798894603951557739f;  // -ln(10000)/512 in f32
#pragma unroll
  for (int f = 0; f < 4; ++f) {
    int n = nb * 64 + f * 16 + l15;
    float dv = expf((float)((n >> 1) * 2) * c1);
    float ben = be[n];
#pragma unroll
    for (int r = 0; r < 4; ++r) {
      int j = jbase + quad * 4 + r;
      float val = 0.f;
      if (trow[r] >= 0) {
        float ph = (float)trow[r] * dv;
        float pe = (n & 1) ? cosf(ph) : sinf(ph);
        val = 8.0f * (acc[f][r] + ben + pe);
      }
      out[((size_t)(b * 4096 + j)) * 512 + n] = val;
    }
  }
}

extern "C" void kernel_launch(void* const* d_in, const int* in_sizes, int n_in,
                              void* d_out, int out_size, void* d_ws, size_t ws_size,
                              hipStream_t stream) {
  const float* data = (const float*)d_in[0];
  const float* v0   = (const float*)d_in[1];
  const float* v1   = (const float*)d_in[2];
  const float* W    = (const float*)d_in[3];
  const float* be   = (const float*)d_in[4];
  const float* Wx   = (const float*)d_in[5];
  const float* Wv   = (const float*)d_in[6];
  const float* bfp  = (const float*)d_in[7];
  char* ws = (char*)d_ws;
  float* out = (float*)d_out;

  hipLaunchKernelGGL(k_prep, dim3(5137), dim3(64), 0, stream, v0, v1, W, be, Wx, Wv, ws);
  hipLaunchKernelGGL(k_decide, dim3(8192), dim3(256), 0, stream,
                     data, bfp, (const char*)ws, (int*)(ws + WS_MASK));
  hipLaunchKernelGGL(k_scan, dim3(8), dim3(1024), 0, stream,
                     (const int*)(ws + WS_MASK), (int*)(ws + WS_SEL), (int*)(ws + WS_LENS));
  hipLaunchKernelGGL(k_gemm, dim3(64, 8, 8), dim3(256), 0, stream,
                     data, be, (const char*)ws, out);
}

// Round 2
// 289.677 us; speedup vs baseline: 1.0351x; 1.0351x over previous
//
#include <hip/hip_runtime.h>
#include <stdint.h>

// PRNG layout for jax.random bits:
//  1 = partitionable counter-mode, bits = y0 ^ y1   (verified correct in round 1)
#define PRNG_VARIANT 1

#define NB 8
#define NT 4096
#define ND 512
#define NH 512
#define NTOK (NB * NT)

typedef __attribute__((ext_vector_type(8))) short short8;
typedef __attribute__((ext_vector_type(4))) float f32x4;

// ---- workspace layout (bytes) ----
#define WS_WEX   0          // 512*2 f64   : W_embed @ Wx
#define WS_PEX   8192       // 4096*2 f64  : (b_embed + pe[t]) @ Wx
#define WS_VWV   73728      // 2*8*2 f64   : v_i @ Wv
#define WS_KEYS  73984      // 4 u32       : fold_in keys
#define WS_MASK  74016      // NTOK i32
#define WS_SEL   205088     // NTOK i32
#define WS_LENS  336160     // 8 i32
#define WS_WT    336192     // 512*512 u16 : bf16 W_embed transposed [n][k]

__device__ inline void threefry2x32(uint32_t k0, uint32_t k1, uint32_t x0, uint32_t x1,
                                    uint32_t& y0, uint32_t& y1) {
  uint32_t ks2 = k0 ^ k1 ^ 0x1BD11BDAu;
  x0 += k0; x1 += k1;
#define TFR(r) { x0 += x1; x1 = (x1 << (r)) | (x1 >> (32 - (r))); x1 ^= x0; }
  TFR(13) TFR(15) TFR(26) TFR(6)   x0 += k1;  x1 += ks2 + 1u;
  TFR(17) TFR(29) TFR(16) TFR(24)  x0 += ks2; x1 += k0 + 2u;
  TFR(13) TFR(15) TFR(26) TFR(6)   x0 += k0;  x1 += k1 + 3u;
  TFR(17) TFR(29) TFR(16) TFR(24)  x0 += k1;  x1 += ks2 + 4u;
  TFR(13) TFR(15) TFR(26) TFR(6)   x0 += ks2; x1 += k0 + 5u;
#undef TFR
  y0 = x0; y1 = x1;
}

// random bits for flat index idx in an array of 65536 uint32 draws
__device__ inline uint32_t rb_bits(uint32_t k0, uint32_t k1, uint32_t idx) {
  uint32_t y0, y1;
  threefry2x32(k0, k1, 0u, idx, y0, y1);
  return y0 ^ y1;
}

__device__ inline double gumbel_from_bits(uint32_t bits) {
  uint32_t m = bits >> 9;
  // jax uniform(minval=tiny32, maxval=1): u = m ? m*2^-23 : FLT_MIN
  float u = m ? (float)m * 1.1920928955078125e-07f : 1.17549435082228751e-38f;
  double lu = log((double)u);
  return -log(-lu);
}

__device__ inline uint16_t f2bf(float f) {
  union { float f; uint32_t u; } v; v.f = f;
  uint32_t u = v.u;
  return (uint16_t)((u + 0x7FFFu + ((u >> 16) & 1u)) >> 16);
}

__device__ inline double wredd(double v) {
#pragma unroll
  for (int o = 32; o > 0; o >>= 1) v += __shfl_xor(v, o, 64);
  return v;
}

// ---- k_prep: fp64 reduced operands + bf16 W^T + PRNG keys ----
__global__ __launch_bounds__(64) void k_prep(
    const float* __restrict__ v0, const float* __restrict__ v1,
    const float* __restrict__ W, const float* __restrict__ be,
    const float* __restrict__ Wx, const float* __restrict__ Wv,
    char* __restrict__ ws) {
  double* Wex = (double*)(ws + WS_WEX);
  double* pex = (double*)(ws + WS_PEX);
  double* vWv = (double*)(ws + WS_VWV);
  uint32_t* keys = (uint32_t*)(ws + WS_KEYS);
  uint16_t* Wt = (uint16_t*)(ws + WS_WT);
  int blk = blockIdx.x;
  int lane = threadIdx.x;

  if (blk < 512) {                       // Wex[d][j] = sum_h W[d][h] * Wx[h][j]
    int d = blk;
    double a0 = 0.0, a1 = 0.0;
    for (int it = 0; it < 8; ++it) {
      int h = it * 64 + lane;
      double w = (double)W[d * 512 + h];
      a0 += w * (double)Wx[2 * h];
      a1 += w * (double)Wx[2 * h + 1];
    }
    a0 = wredd(a0); a1 = wredd(a1);
    if (lane == 0) { Wex[2 * d] = a0; Wex[2 * d + 1] = a1; }
  } else if (blk < 4608) {               // pex[t][j] = sum_h (be[h]+pe[t][h]) * Wx[h][j]
    int t = blk - 512;
    double a0 = 0.0, a1 = 0.0;
    const double c = -9.210340371976184 / 512.0;  // -ln(10000)/H
    for (int it = 0; it < 8; ++it) {
      int h = it * 64 + lane;
      double div = exp((double)((h >> 1) * 2) * c);
      double ph = (double)t * div;
      double pe = (h & 1) ? cos(ph) : sin(ph);
      double pb = pe + (double)be[h];
      a0 += pb * (double)Wx[2 * h];
      a1 += pb * (double)Wx[2 * h + 1];
    }
    a0 = wredd(a0); a1 = wredd(a1);
    if (lane == 0) { pex[2 * t] = a0; pex[2 * t + 1] = a1; }
  } else if (blk < 4624) {               // vWv[i][b][j]
    int q = blk - 4608;
    int i = q >> 3, b = q & 7;
    const float* v = i ? v1 : v0;
    double a0 = 0.0, a1 = 0.0;
    for (int it = 0; it < 8; ++it) {
      int d = it * 64 + lane;
      double x = (double)v[b * 512 + d];
      a0 += x * (double)Wv[2 * d];
      a1 += x * (double)Wv[2 * d + 1];
    }
    a0 = wredd(a0); a1 = wredd(a1);
    if (lane == 0) { vWv[(i * 8 + b) * 2] = a0; vWv[(i * 8 + b) * 2 + 1] = a1; }
  } else if (blk < 5136) {               // Wt[n][k] = bf16(W[k][n])
    int kk = blk - 4624;
    for (int it = 0; it < 8; ++it) {
      int n = it * 64 + lane;
      Wt[(size_t)n * 512 + kk] = f2bf(W[kk * 512 + n]);
    }
  } else {                               // derived keys: fold_in(key(42), i)
    if (lane < 2) {
      uint32_t y0, y1;
      threefry2x32(0u, 42u, 0u, (uint32_t)lane, y0, y1);
      keys[lane * 2] = y0; keys[lane * 2 + 1] = y1;
    }
  }
}

// ---- k_decide: one wave per token; fp64 logits + exact threefry gumbel -> mask ----
__global__ __launch_bounds__(256) void k_decide(
    const float* __restrict__ data, const float* __restrict__ bfp,
    const char* __restrict__ wsc, int* __restrict__ mask) {
  const double* Wex = (const double*)(wsc + WS_WEX);
  const double* pex = (const double*)(wsc + WS_PEX);
  const double* vWv = (const double*)(wsc + WS_VWV);
  const uint32_t* keys = (const uint32_t*)(wsc + WS_KEYS);

  int k = blockIdx.x * 4 + (threadIdx.x >> 6);
  int lane = threadIdx.x & 63;
  int b = k >> 12;
  int t = k & 4095;

  const float4* dp = (const float4*)(data + (size_t)k * 512 + lane * 8);
  float4 f0 = dp[0], f1 = dp[1];
  float xv[8] = {f0.x, f0.y, f0.z, f0.w, f1.x, f1.y, f1.z, f1.w};
  const double* wx = Wex + lane * 16;
  double d0 = 0.0, d1 = 0.0;
#pragma unroll
  for (int u = 0; u < 8; ++u) {
    double x = (double)xv[u];
    d0 += x * wx[2 * u];
    d1 += x * wx[2 * u + 1];
  }
  d0 = wredd(d0); d1 = wredd(d1);

  int dec = 0;
  if (lane < 4) {
    int i = lane >> 1, j = lane & 1;
    double lj = 8.0 * ((j ? d1 : d0) + pex[t * 2 + j]) + vWv[(i * 8 + b) * 2 + j] + (double)bfp[j];
    uint32_t bits = rb_bits(keys[i * 2], keys[i * 2 + 1], (uint32_t)(2 * k + j));
    double z = lj + gumbel_from_bits(bits);
    double zo = __shfl_xor(z, 1, 64);
    dec = (z >= zo) ? 1 : 0;  // meaningful on lanes 0 (i=0) and 2 (i=1): class0 wins
  }
  int dA = __shfl(dec, 0, 64);
  int dB = __shfl(dec, 2, 64);
  if (lane == 0) mask[k] = dA & dB;
}

// ---- k_scan: stable per-row compaction indices ----
__global__ __launch_bounds__(1024) void k_scan(
    const int* __restrict__ mask, int* __restrict__ sel, int* __restrict__ lens) {
  __shared__ int cnt[1024];
  int b = blockIdx.x, tid = threadIdx.x;
  int t0 = tid * 4;
  int m[4], p = 0;
#pragma unroll
  for (int u = 0; u < 4; ++u) { m[u] = mask[b * 4096 + t0 + u]; p += m[u]; }
  cnt[tid] = p;
  __syncthreads();
  for (int off = 1; off < 1024; off <<= 1) {
    int v = (tid >= off) ? cnt[tid - off] : 0;
    __syncthreads();
    cnt[tid] += v;
    __syncthreads();
  }
  int run = cnt[tid] - p;  // exclusive prefix
#pragma unroll
  for (int u = 0; u < 4; ++u) {
    if (m[u]) { sel[b * 4096 + run] = t0 + u; ++run; }
  }
  if (tid == 1023) lens[b] = cnt[1023];
}

// ---- k_gemm: bf16 MFMA on gathered rows; full output coverage (zeros past lens) ----
// Round 2: native trig (__expf/__sinf/__cosf), fast coalesced zero path for
// fully-invalid wave tiles, trig only under the valid-row guard.
__global__ __launch_bounds__(256) void k_gemm(
    const float* __restrict__ data, const float* __restrict__ be,
    const char* __restrict__ wsc, float* __restrict__ out) {
  const uint16_t* Wt = (const uint16_t*)(wsc + WS_WT);
  const int* sel = (const int*)(wsc + WS_SEL);
  const int* lens = (const int*)(wsc + WS_LENS);

  int mb = blockIdx.x, nb = blockIdx.y, b = blockIdx.z;
  int wave = threadIdx.x >> 6, lane = threadIdx.x & 63;
  int quad = lane >> 4, l15 = lane & 15;
  int lensb = lens[b];
  int jbase = mb * 64 + wave * 16;

  if (jbase >= lensb) {
    // all-zero tile: 16 rows x 64 cols; 4 float4 store instrs,
    // each covering 4 rows x 256B contiguous
    float4 z = {0.f, 0.f, 0.f, 0.f};
    int rsub = lane >> 4;         // 0..3
    int cg = lane & 15;           // float4 index within row
#pragma unroll
    for (int it = 0; it < 4; ++it) {
      int j = jbase + it * 4 + rsub;
      float* op = out + ((size_t)(b * 4096 + j)) * 512 + nb * 64 + cg * 4;
      *(float4*)op = z;
    }
    return;
  }

  f32x4 acc[4] = {{0.f,0.f,0.f,0.f},{0.f,0.f,0.f,0.f},{0.f,0.f,0.f,0.f},{0.f,0.f,0.f,0.f}};

  {
    int jA = jbase + l15;
    bool validA = jA < lensb;
    int tA = validA ? sel[b * 4096 + jA] : 0;
    const float* ap = data + ((size_t)b * 4096 + tA) * 512 + quad * 8;
    const uint16_t* bp = Wt + ((size_t)(nb * 64 + l15)) * 512 + quad * 8;
    for (int k0 = 0; k0 < 512; k0 += 32) {
      short8 afrag;
      if (validA) {
        float4 a0 = *(const float4*)(ap + k0);
        float4 a1 = *(const float4*)(ap + k0 + 4);
        afrag[0] = (short)f2bf(a0.x); afrag[1] = (short)f2bf(a0.y);
        afrag[2] = (short)f2bf(a0.z); afrag[3] = (short)f2bf(a0.w);
        afrag[4] = (short)f2bf(a1.x); afrag[5] = (short)f2bf(a1.y);
        afrag[6] = (short)f2bf(a1.z); afrag[7] = (short)f2bf(a1.w);
      } else {
        afrag[0]=0; afrag[1]=0; afrag[2]=0; afrag[3]=0;
        afrag[4]=0; afrag[5]=0; afrag[6]=0; afrag[7]=0;
      }
#pragma unroll
      for (int f = 0; f < 4; ++f) {
        short8 bfrag = *(const short8*)(bp + (size_t)f * 16 * 512 + k0);
        acc[f] = __builtin_amdgcn_mfma_f32_16x16x32_bf16(afrag, bfrag, acc[f], 0, 0, 0);
      }
    }
  }

  int trow[4];
#pragma unroll
  for (int r = 0; r < 4; ++r) {
    int j = jbase + quad * 4 + r;
    trow[r] = (j < lensb) ? sel[b * 4096 + j] : -1;
  }
  const float c1 = -0.01798894603951557739f;  // -ln(10000)/512 in f32
#pragma unroll
  for (int f = 0; f < 4; ++f) {
    int n = nb * 64 + f * 16 + l15;
    float dv = __expf((float)(n & ~1) * c1);
    float ben = be[n];
#pragma unroll
    for (int r = 0; r < 4; ++r) {
      int j = jbase + quad * 4 + r;
      float val = 0.f;
      if (trow[r] >= 0) {
        float ph = (float)trow[r] * dv;
        float pe = (n & 1) ? __cosf(ph) : __sinf(ph);
        val = 8.0f * (acc[f][r] + ben + pe);
      }
      out[((size_t)(b * 4096 + j)) * 512 + n] = val;
    }
  }
}

extern "C" void kernel_launch(void* const* d_in, const int* in_sizes, int n_in,
                              void* d_out, int out_size, void* d_ws, size_t ws_size,
                              hipStream_t stream) {
  const float* data = (const float*)d_in[0];
  const float* v0   = (const float*)d_in[1];
  const float* v1   = (const float*)d_in[2];
  const float* W    = (const float*)d_in[3];
  const float* be   = (const float*)d_in[4];
  const float* Wx   = (const float*)d_in[5];
  const float* Wv   = (const float*)d_in[6];
  const float* bfp  = (const float*)d_in[7];
  char* ws = (char*)d_ws;
  float* out = (float*)d_out;

  hipLaunchKernelGGL(k_prep, dim3(5137), dim3(64), 0, stream, v0, v1, W, be, Wx, Wv, ws);
  hipLaunchKernelGGL(k_decide, dim3(8192), dim3(256), 0, stream,
                     data, bfp, (const char*)ws, (int*)(ws + WS_MASK));
  hipLaunchKernelGGL(k_scan, dim3(8), dim3(1024), 0, stream,
                     (const int*)(ws + WS_MASK), (int*)(ws + WS_SEL), (int*)(ws + WS_LENS));
  hipLaunchKernelGGL(k_gemm, dim3(64, 8, 8), dim3(256), 0, stream,
                     data, be, (const char*)ws, out);
}

// Round 3
// 219.104 us; speedup vs baseline: 1.3684x; 1.3221x over previous
//
#include <hip/hip_runtime.h>
#include <stdint.h>

// PRNG layout: partitionable counter-mode, bits = y0 ^ y1 (verified round 1)

#define NB 8
#define NT 4096
#define ND 512
#define NH 512
#define NTOK (NB * NT)

typedef __attribute__((ext_vector_type(8))) short short8;
typedef __attribute__((ext_vector_type(4))) float f32x4;

// ---- workspace layout (bytes) ----
#define WS_WEX   0          // 512*2 f64   : W_embed @ Wx
#define WS_PEX   8192       // 4096*2 f64  : (b_embed + pe[t]) @ Wx
#define WS_VWV   73728      // 2*8*2 f64   : v_i @ Wv
#define WS_KEYS  73984      // 4 u32       : fold_in keys
#define WS_MASK  74016      // NTOK i32
#define WS_SEL   205088     // NTOK i32
#define WS_LENS  336160     // 8 i32
#define WS_WT    336192     // 512*512 u16 : bf16 W_embed transposed [n][k]
#define WS_APACK 1048576    // 8*4096*512 u16 : packed selected rows (bf16)

__device__ inline void threefry2x32(uint32_t k0, uint32_t k1, uint32_t x0, uint32_t x1,
                                    uint32_t& y0, uint32_t& y1) {
  uint32_t ks2 = k0 ^ k1 ^ 0x1BD11BDAu;
  x0 += k0; x1 += k1;
#define TFR(r) { x0 += x1; x1 = (x1 << (r)) | (x1 >> (32 - (r))); x1 ^= x0; }
  TFR(13) TFR(15) TFR(26) TFR(6)   x0 += k1;  x1 += ks2 + 1u;
  TFR(17) TFR(29) TFR(16) TFR(24)  x0 += ks2; x1 += k0 + 2u;
  TFR(13) TFR(15) TFR(26) TFR(6)   x0 += k0;  x1 += k1 + 3u;
  TFR(17) TFR(29) TFR(16) TFR(24)  x0 += k1;  x1 += ks2 + 4u;
  TFR(13) TFR(15) TFR(26) TFR(6)   x0 += ks2; x1 += k0 + 5u;
#undef TFR
  y0 = x0; y1 = x1;
}

__device__ inline uint32_t rb_bits(uint32_t k0, uint32_t k1, uint32_t idx) {
  uint32_t y0, y1;
  threefry2x32(k0, k1, 0u, idx, y0, y1);
  return y0 ^ y1;
}

__device__ inline double gumbel_from_bits(uint32_t bits) {
  uint32_t m = bits >> 9;
  float u = m ? (float)m * 1.1920928955078125e-07f : 1.17549435082228751e-38f;
  double lu = log((double)u);
  return -log(-lu);
}

__device__ inline uint16_t f2bf(float f) {
  union { float f; uint32_t u; } v; v.f = f;
  uint32_t u = v.u;
  return (uint16_t)((u + 0x7FFFu + ((u >> 16) & 1u)) >> 16);
}

__device__ inline double wredd(double v) {
#pragma unroll
  for (int o = 32; o > 0; o >>= 1) v += __shfl_xor(v, o, 64);
  return v;
}

__device__ inline void gld_lds16(const void* g, void* l) {
  __builtin_amdgcn_global_load_lds(
      (const __attribute__((address_space(1))) void*)g,
      (__attribute__((address_space(3))) void*)l, 16, 0, 0);
}

// ---- k_prep: fp64 reduced operands + bf16 W^T + PRNG keys (UNCHANGED) ----
__global__ __launch_bounds__(64) void k_prep(
    const float* __restrict__ v0, const float* __restrict__ v1,
    const float* __restrict__ W, const float* __restrict__ be,
    const float* __restrict__ Wx, const float* __restrict__ Wv,
    char* __restrict__ ws) {
  double* Wex = (double*)(ws + WS_WEX);
  double* pex = (double*)(ws + WS_PEX);
  double* vWv = (double*)(ws + WS_VWV);
  uint32_t* keys = (uint32_t*)(ws + WS_KEYS);
  uint16_t* Wt = (uint16_t*)(ws + WS_WT);
  int blk = blockIdx.x;
  int lane = threadIdx.x;

  if (blk < 512) {
    int d = blk;
    double a0 = 0.0, a1 = 0.0;
    for (int it = 0; it < 8; ++it) {
      int h = it * 64 + lane;
      double w = (double)W[d * 512 + h];
      a0 += w * (double)Wx[2 * h];
      a1 += w * (double)Wx[2 * h + 1];
    }
    a0 = wredd(a0); a1 = wredd(a1);
    if (lane == 0) { Wex[2 * d] = a0; Wex[2 * d + 1] = a1; }
  } else if (blk < 4608) {
    int t = blk - 512;
    double a0 = 0.0, a1 = 0.0;
    const double c = -9.210340371976184 / 512.0;
    for (int it = 0; it < 8; ++it) {
      int h = it * 64 + lane;
      double div = exp((double)((h >> 1) * 2) * c);
      double ph = (double)t * div;
      double pe = (h & 1) ? cos(ph) : sin(ph);
      double pb = pe + (double)be[h];
      a0 += pb * (double)Wx[2 * h];
      a1 += pb * (double)Wx[2 * h + 1];
    }
    a0 = wredd(a0); a1 = wredd(a1);
    if (lane == 0) { pex[2 * t] = a0; pex[2 * t + 1] = a1; }
  } else if (blk < 4624) {
    int q = blk - 4608;
    int i = q >> 3, b = q & 7;
    const float* v = i ? v1 : v0;
    double a0 = 0.0, a1 = 0.0;
    for (int it = 0; it < 8; ++it) {
      int d = it * 64 + lane;
      double x = (double)v[b * 512 + d];
      a0 += x * (double)Wv[2 * d];
      a1 += x * (double)Wv[2 * d + 1];
    }
    a0 = wredd(a0); a1 = wredd(a1);
    if (lane == 0) { vWv[(i * 8 + b) * 2] = a0; vWv[(i * 8 + b) * 2 + 1] = a1; }
  } else if (blk < 5136) {
    int kk = blk - 4624;
    for (int it = 0; it < 8; ++it) {
      int n = it * 64 + lane;
      Wt[(size_t)n * 512 + kk] = f2bf(W[kk * 512 + n]);
    }
  } else {
    if (lane < 2) {
      uint32_t y0, y1;
      threefry2x32(0u, 42u, 0u, (uint32_t)lane, y0, y1);
      keys[lane * 2] = y0; keys[lane * 2 + 1] = y1;
    }
  }
}

// ---- k_decide: one wave per token; fp64 logits + exact threefry gumbel (UNCHANGED) ----
__global__ __launch_bounds__(256) void k_decide(
    const float* __restrict__ data, const float* __restrict__ bfp,
    const char* __restrict__ wsc, int* __restrict__ mask) {
  const double* Wex = (const double*)(wsc + WS_WEX);
  const double* pex = (const double*)(wsc + WS_PEX);
  const double* vWv = (const double*)(wsc + WS_VWV);
  const uint32_t* keys = (const uint32_t*)(wsc + WS_KEYS);

  int k = blockIdx.x * 4 + (threadIdx.x >> 6);
  int lane = threadIdx.x & 63;
  int b = k >> 12;
  int t = k & 4095;

  const float4* dp = (const float4*)(data + (size_t)k * 512 + lane * 8);
  float4 f0 = dp[0], f1 = dp[1];
  float xv[8] = {f0.x, f0.y, f0.z, f0.w, f1.x, f1.y, f1.z, f1.w};
  const double* wx = Wex + lane * 16;
  double d0 = 0.0, d1 = 0.0;
#pragma unroll
  for (int u = 0; u < 8; ++u) {
    double x = (double)xv[u];
    d0 += x * wx[2 * u];
    d1 += x * wx[2 * u + 1];
  }
  d0 = wredd(d0); d1 = wredd(d1);

  int dec = 0;
  if (lane < 4) {
    int i = lane >> 1, j = lane & 1;
    double lj = 8.0 * ((j ? d1 : d0) + pex[t * 2 + j]) + vWv[(i * 8 + b) * 2 + j] + (double)bfp[j];
    uint32_t bits = rb_bits(keys[i * 2], keys[i * 2 + 1], (uint32_t)(2 * k + j));
    double z = lj + gumbel_from_bits(bits);
    double zo = __shfl_xor(z, 1, 64);
    dec = (z >= zo) ? 1 : 0;
  }
  int dA = __shfl(dec, 0, 64);
  int dB = __shfl(dec, 2, 64);
  if (lane == 0) mask[k] = dA & dB;
}

// ---- k_scan: stable per-row compaction indices (UNCHANGED) ----
__global__ __launch_bounds__(1024) void k_scan(
    const int* __restrict__ mask, int* __restrict__ sel, int* __restrict__ lens) {
  __shared__ int cnt[1024];
  int b = blockIdx.x, tid = threadIdx.x;
  int t0 = tid * 4;
  int m[4], p = 0;
#pragma unroll
  for (int u = 0; u < 4; ++u) { m[u] = mask[b * 4096 + t0 + u]; p += m[u]; }
  cnt[tid] = p;
  __syncthreads();
  for (int off = 1; off < 1024; off <<= 1) {
    int v = (tid >= off) ? cnt[tid - off] : 0;
    __syncthreads();
    cnt[tid] += v;
    __syncthreads();
  }
  int run = cnt[tid] - p;
#pragma unroll
  for (int u = 0; u < 4; ++u) {
    if (m[u]) { sel[b * 4096 + run] = t0 + u; ++run; }
  }
  if (tid == 1023) lens[b] = cnt[1023];
}

// ---- k_gather: pack selected rows -> contiguous bf16 Apack[b][j][k] ----
__global__ __launch_bounds__(256) void k_gather(
    const float* __restrict__ data, const char* __restrict__ wsc,
    uint16_t* __restrict__ Apack) {
  const int* sel = (const int*)(wsc + WS_SEL);
  const int* lens = (const int*)(wsc + WS_LENS);
  int b = blockIdx.y;
  int j = blockIdx.x * 4 + (threadIdx.x >> 6);
  int lane = threadIdx.x & 63;
  if (j >= lens[b]) return;
  int t = sel[b * 4096 + j];
  const float* src = data + ((size_t)b * 4096 + t) * 512 + lane * 8;
  float4 a0 = *(const float4*)src;
  float4 a1 = *(const float4*)(src + 4);
  short8 o;
  o[0] = (short)f2bf(a0.x); o[1] = (short)f2bf(a0.y);
  o[2] = (short)f2bf(a0.z); o[3] = (short)f2bf(a0.w);
  o[4] = (short)f2bf(a1.x); o[5] = (short)f2bf(a1.y);
  o[6] = (short)f2bf(a1.z); o[7] = (short)f2bf(a1.w);
  *(short8*)(Apack + ((size_t)b * 4096 + j) * 512 + lane * 8) = o;
}

// ---- k_gemm v3: m97-style LDS-staged dense bf16 MFMA GEMM + fused epilogue ----
#define BM 128
#define BN 128
#define BK 32

__global__ __launch_bounds__(256) void k_gemm(
    const uint16_t* __restrict__ Apack, const float* __restrict__ be,
    const char* __restrict__ wsc, float* __restrict__ out) {
  const uint16_t* Wt = (const uint16_t*)(wsc + WS_WT);
  const int* sel = (const int*)(wsc + WS_SEL);
  const int* lens = (const int*)(wsc + WS_LENS);

  int mb = blockIdx.x, nb = blockIdx.y, b = blockIdx.z;
  int tid = threadIdx.x;
  int wave = tid >> 6, lane = tid & 63;
  int lensb = lens[b];
  int jbase = mb * BM;

  if (jbase >= lensb) {
    // all-zero 128x128 tile; each store instr: 8 rows x 512B contiguous
    float4 z = {0.f, 0.f, 0.f, 0.f};
    int r0 = tid >> 5;   // 0..7
    int c4 = tid & 31;   // float4 index within 128-col row
#pragma unroll
    for (int it = 0; it < 16; ++it) {
      int j = jbase + it * 8 + r0;
      float* op = out + ((size_t)(b * 4096 + j)) * 512 + nb * BN + c4 * 4;
      *(float4*)op = z;
    }
    return;
  }

  __shared__ __align__(16) uint16_t As[BM * BK];
  __shared__ __align__(16) uint16_t Bs[BN * BK];

  int wm = wave & 1, wn = wave >> 1;
  int quad = lane >> 4, l15 = lane & 15;
  int srow = lane >> 2;          // 0..15 within wave's 16-row staging group
  int scol = (lane & 3) * 8;     // bf16 element offset (16B granule)

  f32x4 acc[4][4] = {};

  const uint16_t* gA = Apack + ((size_t)b * 4096 + jbase) * 512;
  const uint16_t* gB = Wt + (size_t)(nb * BN) * 512;
  uint16_t* lA = As + (size_t)(wave * 16) * BK;  // wave-uniform LDS base
  uint16_t* lB = Bs + (size_t)(wave * 16) * BK;

  for (int k0 = 0; k0 < 512; k0 += BK) {
    // stage 128x32 A and B tiles: global -> LDS, 16B/lane, 2 rounds of 64 rows
    gld_lds16(gA + (size_t)(wave * 16 + srow) * 512 + k0 + scol, lA);
    gld_lds16(gA + (size_t)(64 + wave * 16 + srow) * 512 + k0 + scol, lA + 64 * BK);
    gld_lds16(gB + (size_t)(wave * 16 + srow) * 512 + k0 + scol, lB);
    gld_lds16(gB + (size_t)(64 + wave * 16 + srow) * 512 + k0 + scol, lB + 64 * BK);
    __syncthreads();

    short8 af[4], bf[4];
#pragma unroll
    for (int mi = 0; mi < 4; ++mi)
      af[mi] = *(const short8*)&As[(wm * 64 + mi * 16 + l15) * BK + quad * 8];
#pragma unroll
    for (int ni = 0; ni < 4; ++ni)
      bf[ni] = *(const short8*)&Bs[(wn * 64 + ni * 16 + l15) * BK + quad * 8];
#pragma unroll
    for (int mi = 0; mi < 4; ++mi)
#pragma unroll
      for (int ni = 0; ni < 4; ++ni)
        acc[mi][ni] = __builtin_amdgcn_mfma_f32_16x16x32_bf16(af[mi], bf[ni], acc[mi][ni], 0, 0, 0);
    __syncthreads();
  }

  // fused epilogue: out = 8*(acc + be[n] + pe(t,n)) for j<lensb else 0
  const float c1 = -0.01798894603951557739f;  // -ln(10000)/512
#pragma unroll
  for (int ni = 0; ni < 4; ++ni) {
    int n = nb * BN + wn * 64 + ni * 16 + l15;
    float dv = __expf((float)(n & ~1) * c1);
    float ben = be[n];
#pragma unroll
    for (int mi = 0; mi < 4; ++mi) {
#pragma unroll
      for (int r = 0; r < 4; ++r) {
        int j = jbase + wm * 64 + mi * 16 + quad * 4 + r;
        float val = 0.f;
        if (j < lensb) {
          int t = sel[b * 4096 + j];
          float ph = (float)t * dv;
          float pe = (n & 1) ? __cosf(ph) : __sinf(ph);
          val = 8.0f * (acc[mi][ni][r] + ben + pe);
        }
        out[((size_t)(b * 4096 + j)) * 512 + n] = val;
      }
    }
  }
}

extern "C" void kernel_launch(void* const* d_in, const int* in_sizes, int n_in,
                              void* d_out, int out_size, void* d_ws, size_t ws_size,
                              hipStream_t stream) {
  const float* data = (const float*)d_in[0];
  const float* v0   = (const float*)d_in[1];
  const float* v1   = (const float*)d_in[2];
  const float* W    = (const float*)d_in[3];
  const float* be   = (const float*)d_in[4];
  const float* Wx   = (const float*)d_in[5];
  const float* Wv   = (const float*)d_in[6];
  const float* bfp  = (const float*)d_in[7];
  char* ws = (char*)d_ws;
  float* out = (float*)d_out;
  uint16_t* Apack = (uint16_t*)(ws + WS_APACK);

  hipLaunchKernelGGL(k_prep, dim3(5137), dim3(64), 0, stream, v0, v1, W, be, Wx, Wv, ws);
  hipLaunchKernelGGL(k_decide, dim3(8192), dim3(256), 0, stream,
                     data, bfp, (const char*)ws, (int*)(ws + WS_MASK));
  hipLaunchKernelGGL(k_scan, dim3(8), dim3(1024), 0, stream,
                     (const int*)(ws + WS_MASK), (int*)(ws + WS_SEL), (int*)(ws + WS_LENS));
  hipLaunchKernelGGL(k_gather, dim3(1024, 8), dim3(256), 0, stream,
                     data, (const char*)ws, Apack);
  hipLaunchKernelGGL(k_gemm, dim3(32, 4, 8), dim3(256), 0, stream,
                     Apack, be, (const char*)ws, out);
}